// Round 3
// baseline (1047.072 us; speedup 1.0000x reference)
//
#include <hip/hip_runtime.h>
#include <math.h>

#define NN 12288
#define DD 128
#define EPSF 1e-7f
#define MAXNORM (1.0f - 1e-3f)

typedef __attribute__((ext_vector_type(8))) short short8_t;
typedef __attribute__((ext_vector_type(4))) float float4_t;
typedef unsigned short ushort_t;

__device__ __forceinline__ unsigned short f2bf(float f) {
    unsigned int u = __builtin_bit_cast(unsigned int, f);
    unsigned int r = u + 0x7FFFu + ((u >> 16) & 1u);
    return (unsigned short)(r >> 16);
}

// ---------------- Kernel 1: per-row prep ----------------
__global__ __launch_bounds__(128) void prep_kernel(
    const float* __restrict__ x, const float* __restrict__ a,
    ushort_t* __restrict__ xtb,
    float* __restrict__ wh1, float* __restrict__ wh2)
{
    const int r = blockIdx.x;
    const int t = threadIdx.x;
    const float xv = x[r * DD + t];
    const float a1 = a[t];
    const float a2 = a[DD + t];
    float s0 = xv * xv, s1 = xv * a1, s2 = xv * a2;
    #pragma unroll
    for (int o = 32; o > 0; o >>= 1) {
        s0 += __shfl_xor(s0, o);
        s1 += __shfl_xor(s1, o);
        s2 += __shfl_xor(s2, o);
    }
    __shared__ float red[6];
    const int w = t >> 6;
    if ((t & 63) == 0) { red[w * 3 + 0] = s0; red[w * 3 + 1] = s1; red[w * 3 + 2] = s2; }
    __syncthreads();
    const float sumsq = red[0] + red[3];
    const float d1    = red[1] + red[4];
    const float d2    = red[2] + red[5];
    const float nraw  = sqrtf(sumsq);
    const float nrm   = fminf(fmaxf(nraw, EPSF), 1.0f - EPSF);
    const float scale = atanhf(nrm) / nrm;
    xtb[(size_t)r * DD + t] = f2bf(xv * scale);
    if (t == 0) {
        wh1[r] = scale * d1;
        wh2[r] = scale * d2;
    }
}

// ---------------- Kernel 2: transpose xtb -> xtT[d][j] ----------------
__global__ __launch_bounds__(256) void transpose_kernel(
    const ushort_t* __restrict__ xtb, ushort_t* __restrict__ xtT)
{
    __shared__ ushort_t tile[64][65];
    const int j0 = blockIdx.x * 64;
    const int d0 = blockIdx.y * 64;
    const int t = threadIdx.x;
    const int c = t & 63, r4 = t >> 6;
    #pragma unroll
    for (int k = 0; k < 16; ++k) {
        const int jj = r4 + 4 * k;
        tile[jj][c] = xtb[(size_t)(j0 + jj) * DD + d0 + c];
    }
    __syncthreads();
    #pragma unroll
    for (int k = 0; k < 16; ++k) {
        const int dd = r4 + 4 * k;
        xtT[(size_t)(d0 + dd) * NN + j0 + c] = tile[c][dd];
    }
}

// ---------------- helper: p for 8 consecutive j ----------------
__device__ __forceinline__ void p8(
    const int4& Aa, const int4& Ab, const float4& Wa, const float4& Wb,
    float wh1i, float& lsum, unsigned short pr[8])
{
    const int   av[8] = {Aa.x, Aa.y, Aa.z, Aa.w, Ab.x, Ab.y, Ab.z, Ab.w};
    const float wv[8] = {Wa.x, Wa.y, Wa.z, Wa.w, Wb.x, Wb.y, Wb.z, Wb.w};
    #pragma unroll
    for (int j = 0; j < 8; ++j) {
        const float u  = wh1i + wv[j];
        const float lr = fmaxf(u, 0.2f * u);
        float p = 0.0f;
        if (av[j] > 0) p = __expf(lr);
        lsum += p;
        pr[j] = f2bf(p);
    }
}

// ---------------- Kernel 3: barrier-free MFMA attention ----------------
// grid (NN/64, S), block 256 = 4 waves. Wave w: rows i0+w*16 .. +16, all 128 d.
// A-fragment (p) computed directly in registers in MFMA A-layout; B from global.
__global__ __launch_bounds__(256, 3) void attn_kernel(
    const int* __restrict__ adj,
    const ushort_t* __restrict__ xtT,
    const float* __restrict__ wh1, const float* __restrict__ wh2,
    float* __restrict__ pout, float* __restrict__ plsum, int jlen)
{
    const int t = threadIdx.x;
    const int w = t >> 6;
    const int lane = t & 63;
    const int l15 = lane & 15;
    const int quad = lane >> 4;
    const int i0 = blockIdx.x * 64;
    const int s = blockIdx.y;
    const int jbase = s * jlen;
    const int iw = i0 + w * 16 + l15;      // this lane's A-row

    const float wh1i = wh1[iw];

    float4_t acc[8];
    #pragma unroll
    for (int dt = 0; dt < 8; ++dt) acc[dt] = (float4_t)0.0f;
    float lsum = 0.0f;

    const int* adj_row = adj + (size_t)iw * NN;

    for (int j0 = jbase; j0 < jbase + jlen; j0 += 64) {
        // ---- issue all global loads for this tile ----
        const int4* ap = (const int4*)(adj_row + j0);
        const int4 A0 = ap[quad * 2 + 0];
        const int4 A1 = ap[quad * 2 + 1];
        const int4 A2 = ap[quad * 2 + 8];
        const int4 A3 = ap[quad * 2 + 9];
        const float4* wp = (const float4*)(wh2 + j0);
        const float4 W0 = wp[quad * 2 + 0];
        const float4 W1 = wp[quad * 2 + 1];
        const float4 W2 = wp[quad * 2 + 8];
        const float4 W3 = wp[quad * 2 + 9];

        short8_t bf0[8], bf1[8];
        #pragma unroll
        for (int dt = 0; dt < 8; ++dt) {
            const ushort_t* bp = xtT + (size_t)(dt * 16 + l15) * NN + j0 + quad * 8;
            bf0[dt] = *(const short8_t*)bp;
            bf1[dt] = *(const short8_t*)(bp + 32);
        }

        // ---- p in registers, MFMA A-layout ----
        unsigned short pr0[8], pr1[8];
        p8(A0, A1, W0, W1, wh1i, lsum, pr0);
        p8(A2, A3, W2, W3, wh1i, lsum, pr1);
        short8_t af0, af1;
        #pragma unroll
        for (int j = 0; j < 8; ++j) { af0[j] = (short)pr0[j]; af1[j] = (short)pr1[j]; }

        // ---- MFMA ----
        #pragma unroll
        for (int dt = 0; dt < 8; ++dt)
            acc[dt] = __builtin_amdgcn_mfma_f32_16x16x32_bf16(af0, bf0[dt], acc[dt], 0, 0, 0);
        #pragma unroll
        for (int dt = 0; dt < 8; ++dt)
            acc[dt] = __builtin_amdgcn_mfma_f32_16x16x32_bf16(af1, bf1[dt], acc[dt], 0, 0, 0);
    }

    // ---- lsum: reduce across the 4 quads holding the same row ----
    lsum += __shfl_xor(lsum, 16);
    lsum += __shfl_xor(lsum, 32);
    if (quad == 0) plsum[(size_t)s * NN + iw] = lsum;

    // ---- store fp32 partial numerators (C layout: row=quad*4+reg, col=l15) ----
    #pragma unroll
    for (int dt = 0; dt < 8; ++dt) {
        #pragma unroll
        for (int reg = 0; reg < 4; ++reg) {
            const int i = i0 + w * 16 + quad * 4 + reg;
            pout[((size_t)s * NN + i) * DD + dt * 16 + l15] = acc[dt][reg];
        }
    }
}

// ---------------- Kernel 4: combine partials + normalize + expmap0 + proj ----
__global__ __launch_bounds__(128) void reduce_kernel(
    const float* __restrict__ pout, const float* __restrict__ plsum,
    float* __restrict__ out, int S)
{
    const int i = blockIdx.x;
    const int t = threadIdx.x;
    float v = 0.0f;
    for (int s = 0; s < S; ++s) v += pout[((size_t)s * NN + i) * DD + t];
    float ls = 0.0f;
    for (int s = 0; s < S; ++s) ls += plsum[(size_t)s * NN + i];
    v /= ls;
    float ss = v * v;
    #pragma unroll
    for (int o = 1; o < 64; o <<= 1) ss += __shfl_xor(ss, o);
    __shared__ float r2[2];
    if ((t & 63) == 0) r2[t >> 6] = ss;
    __syncthreads();
    const float total = r2[0] + r2[1];
    const float nraw = sqrtf(total);
    const float nv   = fmaxf(nraw, EPSF);
    const float th   = tanhf(nv);
    const float ysc  = th / nv;
    const float nyr  = ysc * nraw;
    const float ny   = fmaxf(nyr, EPSF);
    const float psc  = (ny > MAXNORM) ? (MAXNORM / ny) : 1.0f;
    const float os   = ysc * psc;
    out[(size_t)i * DD + t] = v * os;
}

extern "C" void kernel_launch(void* const* d_in, const int* in_sizes, int n_in,
                              void* d_out, int out_size, void* d_ws, size_t ws_size,
                              hipStream_t stream) {
    const float* x   = (const float*)d_in[0];
    const int*   adj = (const int*)d_in[1];
    const float* a   = (const float*)d_in[2];
    float* out = (float*)d_out;

    // ---- workspace layout ----
    char* ws = (char*)d_ws;
    ushort_t* xtb = (ushort_t*)ws;  ws += (size_t)NN * DD * sizeof(ushort_t);
    ushort_t* xtT = (ushort_t*)ws;  ws += (size_t)DD * NN * sizeof(ushort_t);
    float* wh1 = (float*)ws;        ws += NN * sizeof(float);
    float* wh2 = (float*)ws;        ws += NN * sizeof(float);

    const size_t fixed = (size_t)(ws - (char*)d_ws);
    const size_t perS  = (size_t)NN * DD * sizeof(float) + NN * sizeof(float);
    // S must divide 192 so jlen is a multiple of 64.
    int S = 1;
    const int cand[7] = {16, 12, 8, 6, 4, 3, 2};
    for (int c = 0; c < 7; ++c) {
        if (fixed + (size_t)cand[c] * perS <= ws_size) { S = cand[c]; break; }
    }
    float* plsum = (float*)ws;      ws += (size_t)S * NN * sizeof(float);
    float* pout  = (float*)ws;

    const int jlen = NN / S;

    prep_kernel<<<NN, 128, 0, stream>>>(x, a, xtb, wh1, wh2);
    transpose_kernel<<<dim3(NN / 64, DD / 64), 256, 0, stream>>>(xtb, xtT);
    attn_kernel<<<dim3(NN / 64, S), 256, 0, stream>>>(
        adj, xtT, wh1, wh2, pout, plsum, jlen);
    reduce_kernel<<<NN, 128, 0, stream>>>(pout, plsum, out, S);
}

// Round 4
// 977.695 us; speedup vs baseline: 1.0710x; 1.0710x over previous
//
#include <hip/hip_runtime.h>
#include <math.h>

#define NN 12288
#define DD 128
#define EPSF 1e-7f
#define MAXNORM (1.0f - 1e-3f)

typedef __attribute__((ext_vector_type(8))) short short8_t;
typedef __attribute__((ext_vector_type(4))) short short4_t;
typedef __attribute__((ext_vector_type(4))) float float4_t;
typedef unsigned short ushort_t;

__device__ __forceinline__ unsigned short f2bf(float f) {
    unsigned int u = __builtin_bit_cast(unsigned int, f);
    unsigned int r = u + 0x7FFFu + ((u >> 16) & 1u);
    return (unsigned short)(r >> 16);
}

// ---------------- Kernel 1: per-row prep ----------------
__global__ __launch_bounds__(128) void prep_kernel(
    const float* __restrict__ x, const float* __restrict__ a,
    ushort_t* __restrict__ xtb,
    float* __restrict__ wh1, float* __restrict__ wh2)
{
    const int r = blockIdx.x;
    const int t = threadIdx.x;
    const float xv = x[r * DD + t];
    const float a1 = a[t];
    const float a2 = a[DD + t];
    float s0 = xv * xv, s1 = xv * a1, s2 = xv * a2;
    #pragma unroll
    for (int o = 32; o > 0; o >>= 1) {
        s0 += __shfl_xor(s0, o);
        s1 += __shfl_xor(s1, o);
        s2 += __shfl_xor(s2, o);
    }
    __shared__ float red[6];
    const int w = t >> 6;
    if ((t & 63) == 0) { red[w * 3 + 0] = s0; red[w * 3 + 1] = s1; red[w * 3 + 2] = s2; }
    __syncthreads();
    const float sumsq = red[0] + red[3];
    const float d1    = red[1] + red[4];
    const float d2    = red[2] + red[5];
    const float nraw  = sqrtf(sumsq);
    const float nrm   = fminf(fmaxf(nraw, EPSF), 1.0f - EPSF);
    const float scale = atanhf(nrm) / nrm;
    xtb[(size_t)r * DD + t] = f2bf(xv * scale);
    if (t == 0) {
        wh1[r] = scale * d1;
        wh2[r] = scale * d2;
    }
}

// ---------------- Kernel 2: build xtB in MFMA-B-fragment-linear layout ----
// For 32-j chunk C, dt (0..7): 1 KB block at (C*8+dt)*1024 bytes; element
// (lane=quad*16+l15, e) = xt[C*32+quad*8+e][dt*16+l15]. B-frag loads in attn
// become base + lane*16: fully contiguous.
__global__ __launch_bounds__(256) void swizzle_kernel(
    const ushort_t* __restrict__ xtb, ushort_t* __restrict__ xtB)
{
    __shared__ ushort_t raw[32 * 136];   // padded row stride 136 shorts
    const int C = blockIdx.x;
    const int t = threadIdx.x;
    // phase 1: coalesced read of [32 j][128 d]
    #pragma unroll
    for (int p = 0; p < 2; ++p) {
        const int idx = p * 256 + t;
        const int j = idx >> 4, cell = idx & 15;
        const uint4 v = *(const uint4*)(xtb + (size_t)(C * 32 + j) * DD + cell * 8);
        *(uint4*)&raw[j * 136 + cell * 8] = v;
    }
    __syncthreads();
    // phase 2: emit fragment-linear cells
    #pragma unroll
    for (int p = 0; p < 2; ++p) {
        const int oc = p * 256 + t;       // 0..511 = dt*64 + lane
        const int dt = oc >> 6;
        const int l6 = oc & 63;
        const int l15 = l6 & 15, q = l6 >> 4;
        short8_t v;
        #pragma unroll
        for (int e = 0; e < 8; ++e)
            v[e] = (short)raw[(q * 8 + e) * 136 + dt * 16 + l15];
        *(short8_t*)(xtB + (size_t)C * 4096 + oc * 8) = v;
    }
}

// ---------------- Kernel 3: contiguous-load MFMA attention ----------------
// grid (NN/128, S), block 256 = 4 independent waves (no __syncthreads).
// Wave: 32 rows, all 128 d. adj read row-contiguous; p redistributed to MFMA
// A-layout via wave-private XOR-swizzled LDS; B from fragment-linear xtB.
__global__ __launch_bounds__(256, 2) void attn_kernel(
    const int* __restrict__ adj,
    const ushort_t* __restrict__ xtB,
    const float* __restrict__ wh1, const float* __restrict__ wh2,
    float* __restrict__ pout, float* __restrict__ plsum, int jlen)
{
    __shared__ ushort_t p_st[4 * 4096];   // 32 KB: 8 KB per wave

    const int t = threadIdx.x;
    const int w = t >> 6, lane = t & 63;
    const int l15 = lane & 15, quad = lane >> 4;
    const int h = lane >> 5, lj = lane & 31;   // half-wave split for adj/p
    const int i0 = blockIdx.x * 128 + w * 32;  // wave's first row
    const int s = blockIdx.y;
    const int jbase = s * jlen;
    const int wb = w * 4096;                   // LDS base (shorts)

    float wh1row[16];
    #pragma unroll
    for (int k = 0; k < 16; ++k) wh1row[k] = wh1[i0 + 2 * k + h];

    float4_t acc[2][8];
    #pragma unroll
    for (int g = 0; g < 2; ++g)
        #pragma unroll
        for (int dt = 0; dt < 8; ++dt) acc[g][dt] = (float4_t)0.0f;
    float lsr[16];
    #pragma unroll
    for (int k = 0; k < 16; ++k) lsr[k] = 0.0f;

    for (int j0 = jbase; j0 < jbase + jlen; j0 += 128) {
        // ---- adj: 16 row-contiguous int4 loads (2 rows per instr) ----
        int4 A[16];
        #pragma unroll
        for (int k = 0; k < 16; ++k)
            A[k] = *(const int4*)(adj + (size_t)(i0 + 2 * k + h) * NN + j0 + lj * 4);
        const float4 Wv = *(const float4*)(wh2 + j0 + lj * 4);

        // ---- p: compute + stage to wave-private LDS (XOR-swizzled) ----
        #pragma unroll
        for (int k = 0; k < 16; ++k) {
            const float u0 = wh1row[k] + Wv.x;
            const float u1 = wh1row[k] + Wv.y;
            const float u2 = wh1row[k] + Wv.z;
            const float u3 = wh1row[k] + Wv.w;
            const float p0 = (A[k].x > 0) ? __expf(fmaxf(u0, 0.2f * u0)) : 0.0f;
            const float p1 = (A[k].y > 0) ? __expf(fmaxf(u1, 0.2f * u1)) : 0.0f;
            const float p2 = (A[k].z > 0) ? __expf(fmaxf(u2, 0.2f * u2)) : 0.0f;
            const float p3 = (A[k].w > 0) ? __expf(fmaxf(u3, 0.2f * u3)) : 0.0f;
            lsr[k] += (p0 + p1) + (p2 + p3);
            short4_t pk;
            pk[0] = (short)f2bf(p0); pk[1] = (short)f2bf(p1);
            pk[2] = (short)f2bf(p2); pk[3] = (short)f2bf(p3);
            const int r = 2 * k + h;
            const int idx = wb + r * 128 + (((lj >> 1) ^ (r & 15)) * 8) + (lj & 1) * 4;
            *(short4_t*)&p_st[idx] = pk;
        }

        // ---- MFMA over 4 32-j chunks; B loads fully lane-contiguous ----
        #pragma unroll
        for (int c = 0; c < 4; ++c) {
            short8_t Bf[8];
            #pragma unroll
            for (int dt = 0; dt < 8; ++dt)
                Bf[dt] = *(const short8_t*)(
                    xtB + ((size_t)(j0 >> 5) + c) * 4096 + dt * 512 + lane * 8);
            const int cellsw = ((c * 4 + quad) ^ l15) * 8;
            const short8_t af0 = *(const short8_t*)&p_st[wb + l15 * 128 + cellsw];
            const short8_t af1 = *(const short8_t*)&p_st[wb + (16 + l15) * 128 + cellsw];
            #pragma unroll
            for (int dt = 0; dt < 8; ++dt) {
                acc[0][dt] = __builtin_amdgcn_mfma_f32_16x16x32_bf16(af0, Bf[dt], acc[0][dt], 0, 0, 0);
                acc[1][dt] = __builtin_amdgcn_mfma_f32_16x16x32_bf16(af1, Bf[dt], acc[1][dt], 0, 0, 0);
            }
        }
    }

    // ---- lsum: reduce each row partial across its 32-lane half ----
    #pragma unroll
    for (int k = 0; k < 16; ++k) {
        float v = lsr[k];
        #pragma unroll
        for (int o = 1; o < 32; o <<= 1) v += __shfl_xor(v, o);
        if (lj == 0) plsum[(size_t)s * NN + i0 + 2 * k + h] = v;
    }

    // ---- store fp32 partial numerators (C layout: row=quad*4+reg, col=l15) --
    #pragma unroll
    for (int g = 0; g < 2; ++g)
        #pragma unroll
        for (int dt = 0; dt < 8; ++dt)
            #pragma unroll
            for (int reg = 0; reg < 4; ++reg) {
                const int i = i0 + g * 16 + quad * 4 + reg;
                pout[((size_t)s * NN + i) * DD + dt * 16 + l15] = acc[g][dt][reg];
            }
}

// ---------------- Kernel 4: combine partials + normalize + expmap0 + proj ----
__global__ __launch_bounds__(128) void reduce_kernel(
    const float* __restrict__ pout, const float* __restrict__ plsum,
    float* __restrict__ out, int S)
{
    const int i = blockIdx.x;
    const int t = threadIdx.x;
    float v = 0.0f;
    for (int s = 0; s < S; ++s) v += pout[((size_t)s * NN + i) * DD + t];
    float ls = 0.0f;
    for (int s = 0; s < S; ++s) ls += plsum[(size_t)s * NN + i];
    v /= ls;
    float ss = v * v;
    #pragma unroll
    for (int o = 1; o < 64; o <<= 1) ss += __shfl_xor(ss, o);
    __shared__ float r2[2];
    if ((t & 63) == 0) r2[t >> 6] = ss;
    __syncthreads();
    const float total = r2[0] + r2[1];
    const float nraw = sqrtf(total);
    const float nv   = fmaxf(nraw, EPSF);
    const float th   = tanhf(nv);
    const float ysc  = th / nv;
    const float nyr  = ysc * nraw;
    const float ny   = fmaxf(nyr, EPSF);
    const float psc  = (ny > MAXNORM) ? (MAXNORM / ny) : 1.0f;
    const float os   = ysc * psc;
    out[(size_t)i * DD + t] = v * os;
}

extern "C" void kernel_launch(void* const* d_in, const int* in_sizes, int n_in,
                              void* d_out, int out_size, void* d_ws, size_t ws_size,
                              hipStream_t stream) {
    const float* x   = (const float*)d_in[0];
    const int*   adj = (const int*)d_in[1];
    const float* a   = (const float*)d_in[2];
    float* out = (float*)d_out;

    // ---- workspace layout ----
    char* ws = (char*)d_ws;
    ushort_t* xtb = (ushort_t*)ws;  ws += (size_t)NN * DD * sizeof(ushort_t);
    ushort_t* xtB = (ushort_t*)ws;  ws += (size_t)NN * DD * sizeof(ushort_t);
    float* wh1 = (float*)ws;        ws += NN * sizeof(float);
    float* wh2 = (float*)ws;        ws += NN * sizeof(float);

    const size_t fixed = (size_t)(ws - (char*)d_ws);
    const size_t perS  = (size_t)NN * DD * sizeof(float) + NN * sizeof(float);
    // S must divide 96 so jlen is a multiple of 128.
    int S = 1;
    const int cand[5] = {8, 6, 4, 3, 2};
    for (int c = 0; c < 5; ++c) {
        if (fixed + (size_t)cand[c] * perS <= ws_size) { S = cand[c]; break; }
    }
    float* plsum = (float*)ws;      ws += (size_t)S * NN * sizeof(float);
    float* pout  = (float*)ws;

    const int jlen = NN / S;

    prep_kernel<<<NN, 128, 0, stream>>>(x, a, xtb, wh1, wh2);
    swizzle_kernel<<<NN / 32, 256, 0, stream>>>(xtb, xtB);
    attn_kernel<<<dim3(NN / 128, S), 256, 0, stream>>>(
        adj, xtB, wh1, wh2, pout, plsum, jlen);
    reduce_kernel<<<NN, 128, 0, stream>>>(pout, plsum, out, S);
}